// Round 4
// baseline (638.435 us; speedup 1.0000x reference)
//
#include <hip/hip_runtime.h>
#include <stdint.h>

typedef __bf16 bf16_t;
typedef bf16_t bf16x8 __attribute__((ext_vector_type(8)));
typedef float f32x4 __attribute__((ext_vector_type(4)));
typedef unsigned int u32;
typedef unsigned short u16;

#define DEV_INLINE __device__ __forceinline__

// ---------- constants ----------
#define S_LEN 2048
#define D_MODEL 4096
#define HQ 32
#define HK 8
#define HD 128
#define NQKV 6144   // HQ*HD + 2*HK*HD
#define QSCALE 0.08838834764831845f

DEV_INLINE u16 f2bf(float x) {
  union { float f; uint32_t u; } v; v.f = x;
  uint32_t r = v.u + 0x7FFFu + ((v.u >> 16) & 1u);  // RNE
  return (u16)(r >> 16);
}
DEV_INLINE float bf2f(u16 x) {
  union { uint32_t u; float f; } v; v.u = ((uint32_t)x) << 16;
  return v.f;
}
DEV_INLINE u32 pack2bf(float a, float b) {
  return (u32)f2bf(a) | ((u32)f2bf(b) << 16);
}

DEV_INLINE void async_load16(const void* g, void* l) {
  __builtin_amdgcn_global_load_lds(
      (const __attribute__((address_space(1))) u32*)g,
      (__attribute__((address_space(3))) u32*)l, 16, 0, 0);
}

DEV_INLINE f32x4 mfma16(bf16x8 a, bf16x8 b, f32x4 c) {
  return __builtin_amdgcn_mfma_f32_16x16x32_bf16(a, b, c, 0, 0, 0);
}

// ---------- prep: 4 weight transposes (f32 (4096,C) -> bf16 (C,4096)) + x cvt ----------
// segments (blocks): [0,16384) wq  [16384,20480) wk  [20480,24576) wv
//                    [24576,40960) wo  [40960,49152) x-cvt
__global__ __launch_bounds__(256) void prep(
    const float* __restrict__ wq, const float* __restrict__ wk,
    const float* __restrict__ wv, const float* __restrict__ wo,
    const float* __restrict__ x,
    u16* __restrict__ wt, u16* __restrict__ wot, u16* __restrict__ xb) {
  int b = blockIdx.x;
  if (b < 40960) {
    const float* src; u16* dst; int C;
    if (b < 16384)      { src = wq; dst = wt;                        C = 4096; }
    else if (b < 20480) { src = wk; dst = wt + 4096L * 4096; C = 1024; b -= 16384; }
    else if (b < 24576) { src = wv; dst = wt + 5120L * 4096; C = 1024; b -= 20480; }
    else                { src = wo; dst = wot;               C = 4096; b -= 24576; }
    __shared__ float tile[32][33];
    int t = threadIdx.x, tx = t & 31, ty = t >> 5;
    int cbn = C >> 5;
    int c0 = (b % cbn) * 32, r0 = (b / cbn) * 32;
#pragma unroll
    for (int i = 0; i < 4; ++i)
      tile[ty + i * 8][tx] = src[(long)(r0 + ty + i * 8) * C + c0 + tx];
    __syncthreads();
#pragma unroll
    for (int i = 0; i < 4; ++i)
      dst[(long)(c0 + ty + i * 8) * 4096 + r0 + tx] = f2bf(tile[tx][ty + i * 8]);
  } else {
    int i = (b - 40960) * 1024 + threadIdx.x * 4;
    float4 v = *(const float4*)(x + i);
    union { u16 s[4]; uint2 u; } o;
    o.s[0] = f2bf(v.x); o.s[1] = f2bf(v.y); o.s[2] = f2bf(v.z); o.s[3] = f2bf(v.w);
    *(uint2*)(xb + i) = o.u;
  }
}

// ---------- GEMM K-loop core (128x128 tile, BK=32, 4 waves) ----------
#define GEMM_KLOOP                                                              \
  __shared__ __attribute__((aligned(16))) u16 As[128 * 32];                     \
  __shared__ __attribute__((aligned(16))) u16 Bs[128 * 32];                     \
  const int tid = threadIdx.x;                                                  \
  const int lane = tid & 63, wave = tid >> 6;                                   \
  const int quad = lane >> 4, l15 = lane & 15;                                  \
  const int bm = blockIdx.y, bn = blockIdx.x;                                   \
  const int wr = (wave >> 1) * 64, wc = (wave & 1) * 64;                        \
  const long arow = (long)bm * 128, brow = (long)bn * 128;                      \
  f32x4 acc[4][4] = {};                                                         \
  for (int k0 = 0; k0 < K; k0 += 32) {                                          \
    _Pragma("unroll")                                                           \
    for (int t = 0; t < 2; ++t) {                                               \
      int c = tid + t * 256;                                                    \
      int row = c >> 2, cc = c & 3;                                             \
      int csrc = cc ^ (row & 3);                                                \
      async_load16(A + (arow + row) * K + k0 + csrc * 8, (u16*)As + c * 8);     \
      async_load16(Bt + (brow + row) * K + k0 + csrc * 8, (u16*)Bs + c * 8);    \
    }                                                                           \
    __syncthreads();                                                            \
    bf16x8 af[4], bfr[4];                                                       \
    _Pragma("unroll")                                                           \
    for (int i = 0; i < 4; ++i) {                                               \
      int row = wr + i * 16 + l15;                                              \
      af[i] = *(const bf16x8*)(As + row * 32 + ((quad ^ (row & 3)) * 8));       \
    }                                                                           \
    _Pragma("unroll")                                                           \
    for (int j = 0; j < 4; ++j) {                                               \
      int row = wc + j * 16 + l15;                                              \
      bfr[j] = *(const bf16x8*)(Bs + row * 32 + ((quad ^ (row & 3)) * 8));      \
    }                                                                           \
    _Pragma("unroll")                                                           \
    for (int i = 0; i < 4; ++i)                                                 \
      _Pragma("unroll")                                                         \
      for (int j = 0; j < 4; ++j)                                               \
        acc[i][j] = mfma16(af[i], bfr[j], acc[i][j]);                           \
    __syncthreads();                                                            \
  }

// ---------- QKV GEMM with fused RoPE epilogue ----------
// A = xb (S, 4096), Bt = wt (6144, 4096). Col ranges: [0,4096) Q -> rope*scale,
// [4096,5120) K -> rope, [5120,6144) V -> store V^T packed.
__global__ __launch_bounds__(256) void gemm_qkv(
    const u16* __restrict__ A, const u16* __restrict__ Bt,
    const float* __restrict__ fcos, const float* __restrict__ fsin,
    u16* __restrict__ Qb, u16* __restrict__ Kb, u16* __restrict__ Vt) {
  const int K = D_MODEL;
  GEMM_KLOOP
  if (bn < 40) {
    // Q or K: RoPE via partner-lane shuffle (cols 2f,2f+1 are lanes l15, l15^1)
    const bool isQ = (bn < 32);
    const float scl = isQ ? QSCALE : 1.0f;
#pragma unroll
    for (int i = 0; i < 4; ++i) {
      int row0 = bm * 128 + wr + i * 16 + quad * 4;
#pragma unroll
      for (int j = 0; j < 4; ++j) {
        int col = bn * 128 + wc + j * 16 + l15;
        int jf = (col & 127) >> 1;
        bool odd = col & 1;
#pragma unroll
        for (int r = 0; r < 4; ++r) {
          int row = row0 + r;
          float a = acc[i][j][r];
          float p = __shfl_xor(a, 1);
          float c = fcos[row * 64 + jf], sn = fsin[row * 64 + jf];
          float o = odd ? (p * sn + a * c) : (a * c - p * sn);
          if (isQ)
            Qb[(long)row * (HQ * HD) + col] = f2bf(o * scl);
          else
            Kb[(long)row * (HK * HD) + (col - 4096)] = f2bf(o);
        }
      }
    }
  } else {
    // V: store transposed (Vt is (1024, S)); 4 consecutive rows pack to 8B
#pragma unroll
    for (int i = 0; i < 4; ++i) {
      int row0 = bm * 128 + wr + i * 16 + quad * 4;
#pragma unroll
      for (int j = 0; j < 4; ++j) {
        int vcol = bn * 128 + wc + j * 16 + l15 - 5120;
        union { u32 w[2]; uint2 u2; } pk;
        pk.w[0] = pack2bf(acc[i][j][0], acc[i][j][1]);
        pk.w[1] = pack2bf(acc[i][j][2], acc[i][j][3]);
        *(uint2*)(Vt + (long)vcol * S_LEN + row0) = pk.u2;
      }
    }
  }
}

// ---------- out-projection GEMM: C f32 = A bf16 @ Bt^T ----------
__global__ __launch_bounds__(256) void gemm_bt(
    const u16* __restrict__ A, const u16* __restrict__ Bt, float* __restrict__ C,
    int M, int N, int K) {
  GEMM_KLOOP
#pragma unroll
  for (int i = 0; i < 4; ++i) {
    int row = bm * 128 + wr + i * 16 + quad * 4;
#pragma unroll
    for (int j = 0; j < 4; ++j) {
      int col = bn * 128 + wc + j * 16 + l15;
#pragma unroll
      for (int r = 0; r < 4; ++r)
        C[(long)(row + r) * N + col] = acc[i][j][r];
    }
  }
}

// ---------- flash attention (transposed formulation) ----------
// grid (16, HQ); 256 thr = 4 waves; q-tile 128, wave owns 32 q-rows (2 N-tiles).
// S^T = K @ Q^T ; O^T = V^T @ P^T. P^T via per-wave LDS, no barrier.
// LDS: Ks 32KB + Vs 32KB + Pts 16KB = 80KB -> 2 blocks/CU.
#define NEG_INF -1e30f
__global__ __launch_bounds__(256, 2) void attn_fwd(
    const u16* __restrict__ Qb, const u16* __restrict__ Kb,
    const u16* __restrict__ Vt, u16* __restrict__ Ob) {
  __shared__ __attribute__((aligned(16))) u16 Ks[128 * 128];    // kpos-major
  __shared__ __attribute__((aligned(16))) u16 Vs[128 * 128];    // d-major (V^T)
  __shared__ __attribute__((aligned(16))) u16 Pts[4][16 * 128]; // per-wave P^T
  const int tid = threadIdx.x;
  const int lane = tid & 63, wave = tid >> 6;
  const int quad = lane >> 4, l15 = lane & 15;
  const int u = 15 - blockIdx.x;        // heavy tiles dispatch first
  const int h = blockIdx.y, hk = h >> 2;
  const int swz = 2 * (l15 & 7);

  bf16x8 qf[2][4];
#pragma unroll
  for (int n = 0; n < 2; ++n) {
    const u16* qrow = Qb + (long)(u * 128 + wave * 32 + n * 16 + l15) * (HQ * HD)
                      + h * HD + quad * 8;
#pragma unroll
    for (int ks = 0; ks < 4; ++ks) qf[n][ks] = *(const bf16x8*)(qrow + ks * 32);
  }

  float m_run[2] = {NEG_INF, NEG_INF}, l_run[2] = {0.f, 0.f};
  f32x4 oacc[8][2] = {};

  for (int j = 0; j <= u; ++j) {
#pragma unroll
    for (int it = 0; it < 8; ++it) {
      int c = tid + it * 256;
      int row = c >> 4, cc = c & 15, csrc = cc ^ (row & 15);
      async_load16(Kb + (long)(j * 128 + row) * (HK * HD) + hk * HD + csrc * 8,
                   (u16*)Ks + c * 8);
      async_load16(Vt + (long)(hk * HD + row) * S_LEN + j * 128 + csrc * 8,
                   (u16*)Vs + c * 8);
    }
    __syncthreads();

    f32x4 sc[8][2] = {};
#pragma unroll
    for (int ks = 0; ks < 4; ++ks)
#pragma unroll
      for (int tj = 0; tj < 8; ++tj) {
        int row = tj * 16 + l15;
        bf16x8 kf = *(const bf16x8*)(Ks + row * 128 + (((ks * 4 + quad) ^ (row & 15)) * 8));
        sc[tj][0] = mfma16(kf, qf[0][ks], sc[tj][0]);
        sc[tj][1] = mfma16(kf, qf[1][ks], sc[tj][1]);
      }

    const bool diag = (j == u);
#pragma unroll
    for (int n = 0; n < 2; ++n) {
      int qloc = wave * 32 + n * 16 + l15;
      if (diag) {
#pragma unroll
        for (int tj = 0; tj < 8; ++tj)
#pragma unroll
          for (int r = 0; r < 4; ++r)
            if (tj * 16 + quad * 4 + r > qloc) sc[tj][n][r] = NEG_INF;
      }
      float m = NEG_INF;
#pragma unroll
      for (int tj = 0; tj < 8; ++tj)
#pragma unroll
        for (int r = 0; r < 4; ++r) m = fmaxf(m, sc[tj][n][r]);
      m = fmaxf(m, __shfl_xor(m, 16));
      m = fmaxf(m, __shfl_xor(m, 32));
      float mnew = fmaxf(m_run[n], m);
      float alpha = __expf(m_run[n] - mnew);
      m_run[n] = mnew;
      float rs = 0.f;
#pragma unroll
      for (int tj = 0; tj < 8; ++tj)
#pragma unroll
        for (int r = 0; r < 4; ++r) {
          float p = __expf(sc[tj][n][r] - mnew);
          sc[tj][n][r] = p;
          rs += p;
        }
      rs += __shfl_xor(rs, 16);
      rs += __shfl_xor(rs, 32);
      l_run[n] = l_run[n] * alpha + rs;
#pragma unroll
      for (int tj = 0; tj < 8; ++tj) oacc[tj][n] *= alpha;
    }

    u16* pw = &Pts[wave][0];
    bf16x8 pf0[4], pf1[4];
#pragma unroll
    for (int tj = 0; tj < 8; ++tj) {
      union { u32 w[2]; uint2 u2; } pk;
      pk.w[0] = pack2bf(sc[tj][0][0], sc[tj][0][1]);
      pk.w[1] = pack2bf(sc[tj][0][2], sc[tj][0][3]);
      *(uint2*)(pw + l15 * 128 + (((tj * 4 + quad) ^ swz) * 4)) = pk.u2;
    }
    __asm__ volatile("s_waitcnt lgkmcnt(0)" ::: "memory");
#pragma unroll
    for (int ks = 0; ks < 4; ++ks)
      pf0[ks] = *(const bf16x8*)(pw + l15 * 128 + (((ks * 8 + quad * 2) ^ swz) * 4));
    __asm__ volatile("s_waitcnt lgkmcnt(0)" ::: "memory");
#pragma unroll
    for (int tj = 0; tj < 8; ++tj) {
      union { u32 w[2]; uint2 u2; } pk;
      pk.w[0] = pack2bf(sc[tj][1][0], sc[tj][1][1]);
      pk.w[1] = pack2bf(sc[tj][1][2], sc[tj][1][3]);
      *(uint2*)(pw + l15 * 128 + (((tj * 4 + quad) ^ swz) * 4)) = pk.u2;
    }
    __asm__ volatile("s_waitcnt lgkmcnt(0)" ::: "memory");
#pragma unroll
    for (int ks = 0; ks < 4; ++ks)
      pf1[ks] = *(const bf16x8*)(pw + l15 * 128 + (((ks * 8 + quad * 2) ^ swz) * 4));

#pragma unroll
    for (int ks = 0; ks < 4; ++ks)
#pragma unroll
      for (int tj = 0; tj < 8; ++tj) {
        int row = tj * 16 + l15;
        bf16x8 vf = *(const bf16x8*)(Vs + row * 128 + (((ks * 4 + quad) ^ (row & 15)) * 8));
        oacc[tj][0] = mfma16(vf, pf0[ks], oacc[tj][0]);
        oacc[tj][1] = mfma16(vf, pf1[ks], oacc[tj][1]);
      }
    __syncthreads();
  }

#pragma unroll
  for (int n = 0; n < 2; ++n) {
    float inv_l = 1.0f / l_run[n];
    long grow = u * 128 + wave * 32 + n * 16 + l15;
#pragma unroll
    for (int tj = 0; tj < 8; ++tj) {
      int gcol = h * HD + tj * 16 + quad * 4;
      union { u32 w[2]; uint2 u2; } pk;
      pk.w[0] = pack2bf(oacc[tj][n][0] * inv_l, oacc[tj][n][1] * inv_l);
      pk.w[1] = pack2bf(oacc[tj][n][2] * inv_l, oacc[tj][n][3] * inv_l);
      *(uint2*)(Ob + grow * (HQ * HD) + gcol) = pk.u2;
    }
  }
}

// ---------- host ----------
#define MB (1024L * 1024L)

extern "C" void kernel_launch(void* const* d_in, const int* in_sizes, int n_in,
                              void* d_out, int out_size, void* d_ws, size_t ws_size,
                              hipStream_t stream) {
  const float* x    = (const float*)d_in[0];
  const float* fcos = (const float*)d_in[1];
  const float* fsin = (const float*)d_in[2];
  const float* wq   = (const float*)d_in[3];
  const float* wk   = (const float*)d_in[4];
  const float* wv   = (const float*)d_in[5];
  const float* wo   = (const float*)d_in[6];
  float* out = (float*)d_out;

  char* ws = (char*)d_ws;
  u16* wt    = (u16*)(ws + 0 * MB);     // 48 MB: [wq^T|wk^T|wv^T] (6144,4096)
  u16* wot   = (u16*)(ws + 48 * MB);    // 32 MB: wo^T (4096,4096)
  u16* xb    = (u16*)(ws + 80 * MB);    // 16 MB
  u16* Qb    = (u16*)(ws + 96 * MB);    // 16 MB (S, 4096) roped*scale
  u16* Kb    = (u16*)(ws + 112 * MB);   //  4 MB (S, 1024) roped
  u16* Vt    = (u16*)(ws + 116 * MB);   //  4 MB (1024, S)
  u16* attnb = (u16*)(ws + 120 * MB);   // 16 MB

  // 1) all weight transposes + x cvt
  prep<<<49152, 256, 0, stream>>>(wq, wk, wv, wo, x, wt, wot, xb);

  // 2) fused QKV projection + RoPE + V^T
  gemm_qkv<<<dim3(NQKV / 128, S_LEN / 128), 256, 0, stream>>>(
      xb, wt, fcos, fsin, Qb, Kb, Vt);

  // 3) flash attention
  attn_fwd<<<dim3(16, HQ), 256, 0, stream>>>(Qb, Kb, Vt, attnb);

  // 4) out = attn @ wo
  gemm_bt<<<dim3(D_MODEL / 128, S_LEN / 128), 256, 0, stream>>>(
      attnb, wot, out, S_LEN, D_MODEL, HQ * HD);
}

// Round 5
// 615.092 us; speedup vs baseline: 1.0380x; 1.0380x over previous
//
#include <hip/hip_runtime.h>
#include <stdint.h>

typedef __bf16 bf16_t;
typedef bf16_t bf16x8 __attribute__((ext_vector_type(8)));
typedef float f32x4 __attribute__((ext_vector_type(4)));
typedef unsigned int u32;
typedef unsigned short u16;

#define DEV_INLINE __device__ __forceinline__

// ---------- constants ----------
#define S_LEN 2048
#define D_MODEL 4096
#define HQ 32
#define HK 8
#define HD 128
#define NQKV 6144   // HQ*HD + 2*HK*HD
#define QSCALE 0.08838834764831845f

DEV_INLINE u16 f2bf(float x) {
  union { float f; uint32_t u; } v; v.f = x;
  uint32_t r = v.u + 0x7FFFu + ((v.u >> 16) & 1u);  // RNE
  return (u16)(r >> 16);
}
DEV_INLINE float bf2f(u16 x) {
  union { uint32_t u; float f; } v; v.u = ((uint32_t)x) << 16;
  return v.f;
}
DEV_INLINE u32 pack2bf(float a, float b) {
  return (u32)f2bf(a) | ((u32)f2bf(b) << 16);
}

DEV_INLINE void async_load16(const void* g, void* l) {
  __builtin_amdgcn_global_load_lds(
      (const __attribute__((address_space(1))) u32*)g,
      (__attribute__((address_space(3))) u32*)l, 16, 0, 0);
}

DEV_INLINE f32x4 mfma16(bf16x8 a, bf16x8 b, f32x4 c) {
  return __builtin_amdgcn_mfma_f32_16x16x32_bf16(a, b, c, 0, 0, 0);
}

// RoPE-pair permutation: logical col L within a 64-group -> physical row p,
// such that physical p = 16j + l carries L = 2*((j>>1)*16 + l) + (j&1).
// Then lanes hold pairs (2f,2f+1) in adjacent acc j-slots (no cross-lane).
DEV_INLINE int perm64(int g) {
  int e = g & 1, t = g >> 1;
  return ((t >> 4) * 2 + e) * 16 + (t & 15);
}

// ---------- prep: 4 weight transposes (f32 (4096,C) -> bf16 (C,4096)) + x cvt ----------
// segments (blocks): [0,16384) wq  [16384,20480) wk  [20480,24576) wv
//                    [24576,40960) wo  [40960,49152) x-cvt
// wq/wk rows are stored RoPE-pair-permuted (perm64 within 64-col groups).
__global__ __launch_bounds__(256) void prep(
    const float* __restrict__ wq, const float* __restrict__ wk,
    const float* __restrict__ wv, const float* __restrict__ wo,
    const float* __restrict__ x,
    u16* __restrict__ wt, u16* __restrict__ wot, u16* __restrict__ xb) {
  int b = blockIdx.x;
  if (b < 40960) {
    const float* src; u16* dst; int C; bool permQK;
    if (b < 16384)      { src = wq; dst = wt;               C = 4096; permQK = true; }
    else if (b < 20480) { src = wk; dst = wt + 4096L * 4096; C = 1024; permQK = true;  b -= 16384; }
    else if (b < 24576) { src = wv; dst = wt + 5120L * 4096; C = 1024; permQK = false; b -= 20480; }
    else                { src = wo; dst = wot;              C = 4096; permQK = false; b -= 24576; }
    __shared__ float tile[32][33];
    int t = threadIdx.x, tx = t & 31, ty = t >> 5;
    int cbn = C >> 5;
    int c0 = (b % cbn) * 32, r0 = (b / cbn) * 32;
#pragma unroll
    for (int i = 0; i < 4; ++i)
      tile[ty + i * 8][tx] = src[(long)(r0 + ty + i * 8) * C + c0 + tx];
    __syncthreads();
#pragma unroll
    for (int i = 0; i < 4; ++i) {
      int c = c0 + ty + i * 8;
      int p = permQK ? ((c & ~63) | perm64(c & 63)) : c;
      dst[(long)p * 4096 + r0 + tx] = f2bf(tile[tx][ty + i * 8]);
    }
  } else {
    int i = (b - 40960) * 1024 + threadIdx.x * 4;
    float4 v = *(const float4*)(x + i);
    union { u16 s[4]; uint2 u; } o;
    o.s[0] = f2bf(v.x); o.s[1] = f2bf(v.y); o.s[2] = f2bf(v.z); o.s[3] = f2bf(v.w);
    *(uint2*)(xb + i) = o.u;
  }
}

// ---------- GEMM K-loop core (128x128 tile, BK=32, 4 waves) ----------
#define GEMM_KLOOP                                                              \
  __shared__ __attribute__((aligned(16))) u16 As[128 * 32];                     \
  __shared__ __attribute__((aligned(16))) u16 Bs[128 * 32];                     \
  const int tid = threadIdx.x;                                                  \
  const int lane = tid & 63, wave = tid >> 6;                                   \
  const int quad = lane >> 4, l15 = lane & 15;                                  \
  const int bm = blockIdx.y, bn = blockIdx.x;                                   \
  const int wr = (wave >> 1) * 64, wc = (wave & 1) * 64;                        \
  const long arow = (long)bm * 128, brow = (long)bn * 128;                      \
  f32x4 acc[4][4] = {};                                                         \
  for (int k0 = 0; k0 < K; k0 += 32) {                                          \
    _Pragma("unroll")                                                           \
    for (int t = 0; t < 2; ++t) {                                               \
      int c = tid + t * 256;                                                    \
      int row = c >> 2, cc = c & 3;                                             \
      int csrc = cc ^ (row & 3);                                                \
      async_load16(A + (arow + row) * K + k0 + csrc * 8, (u16*)As + c * 8);     \
      async_load16(Bt + (brow + row) * K + k0 + csrc * 8, (u16*)Bs + c * 8);    \
    }                                                                           \
    __syncthreads();                                                            \
    bf16x8 af[4], bfr[4];                                                       \
    _Pragma("unroll")                                                           \
    for (int i = 0; i < 4; ++i) {                                               \
      int row = wr + i * 16 + l15;                                              \
      af[i] = *(const bf16x8*)(As + row * 32 + ((quad ^ (row & 3)) * 8));       \
    }                                                                           \
    _Pragma("unroll")                                                           \
    for (int j = 0; j < 4; ++j) {                                               \
      int row = wc + j * 16 + l15;                                              \
      bfr[j] = *(const bf16x8*)(Bs + row * 32 + ((quad ^ (row & 3)) * 8));      \
    }                                                                           \
    _Pragma("unroll")                                                           \
    for (int i = 0; i < 4; ++i)                                                 \
      _Pragma("unroll")                                                         \
      for (int j = 0; j < 4; ++j)                                               \
        acc[i][j] = mfma16(af[i], bfr[j], acc[i][j]);                           \
    __syncthreads();                                                            \
  }

// ---------- QKV GEMM with fused lane-local RoPE epilogue ----------
// A = xb (S, 4096), Bt = wt (6144, 4096) with Q/K rows perm64-permuted.
// bn<32: Q (rope*scale) ; bn 32..39: K (rope) ; bn>=40: V -> V^T packed.
__global__ __launch_bounds__(256) void gemm_qkv(
    const u16* __restrict__ A, const u16* __restrict__ Bt,
    const float* __restrict__ fcos, const float* __restrict__ fsin,
    u16* __restrict__ Qb, u16* __restrict__ Kb, u16* __restrict__ Vt) {
  const int K = D_MODEL;
  GEMM_KLOOP
  if (bn < 40) {
    const bool isQ = (bn < 32);
    const float scl = isQ ? QSCALE : 1.0f;
    u16* dst = isQ ? Qb : Kb;
    const int ncols = isQ ? (HQ * HD) : (HK * HD);
    const int cbase = isQ ? (bn * 128 + wc) : (bn * 128 + wc - 4096);
#pragma unroll
    for (int hh = 0; hh < 2; ++hh) {
      int f_local = hh * 16 + l15;
      int jf = (wc >> 1) + f_local;            // (cbase&127)>>1 + f_local
#pragma unroll
      for (int i = 0; i < 4; ++i) {
        int row0 = bm * 128 + wr + i * 16 + quad * 4;
#pragma unroll
        for (int r = 0; r < 4; ++r) {
          int row = row0 + r;
          float c = fcos[row * 64 + jf], sn = fsin[row * 64 + jf];
          float a0 = acc[i][2 * hh][r] * scl;
          float a1 = acc[i][2 * hh + 1][r] * scl;
          *(u32*)(dst + (long)row * ncols + cbase + 2 * f_local) =
              pack2bf(a0 * c - a1 * sn, a0 * sn + a1 * c);
        }
      }
    }
  } else {
    // V: store transposed (Vt is (1024, S)); 4 consecutive rows pack to 8B
#pragma unroll
    for (int i = 0; i < 4; ++i) {
      int row0 = bm * 128 + wr + i * 16 + quad * 4;
#pragma unroll
      for (int j = 0; j < 4; ++j) {
        int vcol = bn * 128 + wc + j * 16 + l15 - 5120;
        union { u32 w[2]; uint2 u2; } pk;
        pk.w[0] = pack2bf(acc[i][j][0], acc[i][j][1]);
        pk.w[1] = pack2bf(acc[i][j][2], acc[i][j][3]);
        *(uint2*)(Vt + (long)vcol * S_LEN + row0) = pk.u2;
      }
    }
  }
}

// ---------- out-projection GEMM: C f32 = A bf16 @ Bt^T ----------
__global__ __launch_bounds__(256) void gemm_bt(
    const u16* __restrict__ A, const u16* __restrict__ Bt, float* __restrict__ C,
    int M, int N, int K) {
  GEMM_KLOOP
#pragma unroll
  for (int i = 0; i < 4; ++i) {
    int row = bm * 128 + wr + i * 16 + quad * 4;
#pragma unroll
    for (int j = 0; j < 4; ++j) {
      int col = bn * 128 + wc + j * 16 + l15;
#pragma unroll
      for (int r = 0; r < 4; ++r)
        C[(long)(row + r) * N + col] = acc[i][j][r];
    }
  }
}

// ---------- flash attention (transposed formulation) ----------
// grid (16, HQ); 256 thr = 4 waves; q-tile 128, wave owns 32 q-rows (2 N-tiles).
// S^T = K @ Q^T ; O^T = V^T @ P^T. P^T via per-wave LDS, no barrier.
// LDS: Ks 32KB + Vs 32KB + Pts 16KB = 80KB -> 2 blocks/CU.
#define NEG_INF -1e30f
__global__ __launch_bounds__(256, 2) void attn_fwd(
    const u16* __restrict__ Qb, const u16* __restrict__ Kb,
    const u16* __restrict__ Vt, u16* __restrict__ Ob) {
  __shared__ __attribute__((aligned(16))) u16 Ks[128 * 128];    // kpos-major
  __shared__ __attribute__((aligned(16))) u16 Vs[128 * 128];    // d-major (V^T)
  __shared__ __attribute__((aligned(16))) u16 Pts[4][16 * 128]; // per-wave P^T
  const int tid = threadIdx.x;
  const int lane = tid & 63, wave = tid >> 6;
  const int quad = lane >> 4, l15 = lane & 15;
  const int u = 15 - blockIdx.x;        // heavy tiles dispatch first
  const int h = blockIdx.y, hk = h >> 2;
  const int swz = 2 * (l15 & 7);

  bf16x8 qf[2][4];
#pragma unroll
  for (int n = 0; n < 2; ++n) {
    const u16* qrow = Qb + (long)(u * 128 + wave * 32 + n * 16 + l15) * (HQ * HD)
                      + h * HD + quad * 8;
#pragma unroll
    for (int ks = 0; ks < 4; ++ks) qf[n][ks] = *(const bf16x8*)(qrow + ks * 32);
  }

  float m_run[2] = {NEG_INF, NEG_INF}, l_run[2] = {0.f, 0.f};
  f32x4 oacc[8][2] = {};

  for (int j = 0; j <= u; ++j) {
#pragma unroll
    for (int it = 0; it < 8; ++it) {
      int c = tid + it * 256;
      int row = c >> 4, cc = c & 15, csrc = cc ^ (row & 15);
      async_load16(Kb + (long)(j * 128 + row) * (HK * HD) + hk * HD + csrc * 8,
                   (u16*)Ks + c * 8);
      async_load16(Vt + (long)(hk * HD + row) * S_LEN + j * 128 + csrc * 8,
                   (u16*)Vs + c * 8);
    }
    __syncthreads();

    f32x4 sc[8][2] = {};
#pragma unroll
    for (int ks = 0; ks < 4; ++ks)
#pragma unroll
      for (int tj = 0; tj < 8; ++tj) {
        int row = tj * 16 + l15;
        bf16x8 kf = *(const bf16x8*)(Ks + row * 128 + (((ks * 4 + quad) ^ (row & 15)) * 8));
        sc[tj][0] = mfma16(kf, qf[0][ks], sc[tj][0]);
        sc[tj][1] = mfma16(kf, qf[1][ks], sc[tj][1]);
      }

    const bool diag = (j == u);
#pragma unroll
    for (int n = 0; n < 2; ++n) {
      int qloc = wave * 32 + n * 16 + l15;
      if (diag) {
#pragma unroll
        for (int tj = 0; tj < 8; ++tj)
#pragma unroll
          for (int r = 0; r < 4; ++r)
            if (tj * 16 + quad * 4 + r > qloc) sc[tj][n][r] = NEG_INF;
      }
      float m = NEG_INF;
#pragma unroll
      for (int tj = 0; tj < 8; ++tj)
#pragma unroll
        for (int r = 0; r < 4; ++r) m = fmaxf(m, sc[tj][n][r]);
      m = fmaxf(m, __shfl_xor(m, 16));
      m = fmaxf(m, __shfl_xor(m, 32));
      float mnew = fmaxf(m_run[n], m);
      float alpha = __expf(m_run[n] - mnew);
      m_run[n] = mnew;
      float rs = 0.f;
#pragma unroll
      for (int tj = 0; tj < 8; ++tj)
#pragma unroll
        for (int r = 0; r < 4; ++r) {
          float p = __expf(sc[tj][n][r] - mnew);
          sc[tj][n][r] = p;
          rs += p;
        }
      rs += __shfl_xor(rs, 16);
      rs += __shfl_xor(rs, 32);
      l_run[n] = l_run[n] * alpha + rs;
#pragma unroll
      for (int tj = 0; tj < 8; ++tj) oacc[tj][n] *= alpha;
    }

    u16* pw = &Pts[wave][0];
    bf16x8 pf0[4], pf1[4];
#pragma unroll
    for (int tj = 0; tj < 8; ++tj) {
      union { u32 w[2]; uint2 u2; } pk;
      pk.w[0] = pack2bf(sc[tj][0][0], sc[tj][0][1]);
      pk.w[1] = pack2bf(sc[tj][0][2], sc[tj][0][3]);
      *(uint2*)(pw + l15 * 128 + (((tj * 4 + quad) ^ swz) * 4)) = pk.u2;
    }
    __asm__ volatile("s_waitcnt lgkmcnt(0)" ::: "memory");
#pragma unroll
    for (int ks = 0; ks < 4; ++ks)
      pf0[ks] = *(const bf16x8*)(pw + l15 * 128 + (((ks * 8 + quad * 2) ^ swz) * 4));
    __asm__ volatile("s_waitcnt lgkmcnt(0)" ::: "memory");
#pragma unroll
    for (int tj = 0; tj < 8; ++tj) {
      union { u32 w[2]; uint2 u2; } pk;
      pk.w[0] = pack2bf(sc[tj][1][0], sc[tj][1][1]);
      pk.w[1] = pack2bf(sc[tj][1][2], sc[tj][1][3]);
      *(uint2*)(pw + l15 * 128 + (((tj * 4 + quad) ^ swz) * 4)) = pk.u2;
    }
    __asm__ volatile("s_waitcnt lgkmcnt(0)" ::: "memory");
#pragma unroll
    for (int ks = 0; ks < 4; ++ks)
      pf1[ks] = *(const bf16x8*)(pw + l15 * 128 + (((ks * 8 + quad * 2) ^ swz) * 4));

#pragma unroll
    for (int ks = 0; ks < 4; ++ks)
#pragma unroll
      for (int tj = 0; tj < 8; ++tj) {
        int row = tj * 16 + l15;
        bf16x8 vf = *(const bf16x8*)(Vs + row * 128 + (((ks * 4 + quad) ^ (row & 15)) * 8));
        oacc[tj][0] = mfma16(vf, pf0[ks], oacc[tj][0]);
        oacc[tj][1] = mfma16(vf, pf1[ks], oacc[tj][1]);
      }
    __syncthreads();
  }

#pragma unroll
  for (int n = 0; n < 2; ++n) {
    float inv_l = 1.0f / l_run[n];
    long grow = u * 128 + wave * 32 + n * 16 + l15;
#pragma unroll
    for (int tj = 0; tj < 8; ++tj) {
      int gcol = h * HD + tj * 16 + quad * 4;
      union { u32 w[2]; uint2 u2; } pk;
      pk.w[0] = pack2bf(oacc[tj][n][0] * inv_l, oacc[tj][n][1] * inv_l);
      pk.w[1] = pack2bf(oacc[tj][n][2] * inv_l, oacc[tj][n][3] * inv_l);
      *(uint2*)(Ob + grow * (HQ * HD) + gcol) = pk.u2;
    }
  }
}

// ---------- host ----------
#define MB (1024L * 1024L)

extern "C" void kernel_launch(void* const* d_in, const int* in_sizes, int n_in,
                              void* d_out, int out_size, void* d_ws, size_t ws_size,
                              hipStream_t stream) {
  const float* x    = (const float*)d_in[0];
  const float* fcos = (const float*)d_in[1];
  const float* fsin = (const float*)d_in[2];
  const float* wq   = (const float*)d_in[3];
  const float* wk   = (const float*)d_in[4];
  const float* wv   = (const float*)d_in[5];
  const float* wo   = (const float*)d_in[6];
  float* out = (float*)d_out;

  char* ws = (char*)d_ws;
  u16* wt    = (u16*)(ws + 0 * MB);     // 48 MB: [wq^T|wk^T|wv^T] (6144,4096), Q/K perm64
  u16* wot   = (u16*)(ws + 48 * MB);    // 32 MB: wo^T (4096,4096)
  u16* xb    = (u16*)(ws + 80 * MB);    // 16 MB
  u16* Qb    = (u16*)(ws + 96 * MB);    // 16 MB (S, 4096) roped*scale
  u16* Kb    = (u16*)(ws + 112 * MB);   //  4 MB (S, 1024) roped
  u16* Vt    = (u16*)(ws + 116 * MB);   //  4 MB (1024, S)
  u16* attnb = (u16*)(ws + 120 * MB);   // 16 MB

  // 1) all weight transposes (Q/K rope-pair-permuted) + x cvt
  prep<<<49152, 256, 0, stream>>>(wq, wk, wv, wo, x, wt, wot, xb);

  // 2) fused QKV projection + lane-local RoPE + V^T
  gemm_qkv<<<dim3(NQKV / 128, S_LEN / 128), 256, 0, stream>>>(
      xb, wt, fcos, fsin, Qb, Kb, Vt);

  // 3) flash attention
  attn_fwd<<<dim3(16, HQ), 256, 0, stream>>>(Qb, Kb, Vt, attnb);

  // 4) out = attn @ wo
  gemm_bt<<<dim3(D_MODEL / 128, S_LEN / 128), 256, 0, stream>>>(
      attnb, wot, out, S_LEN, D_MODEL, HQ * HD);
}

// Round 6
// 612.205 us; speedup vs baseline: 1.0428x; 1.0047x over previous
//
#include <hip/hip_runtime.h>
#include <stdint.h>

typedef __bf16 bf16_t;
typedef bf16_t bf16x8 __attribute__((ext_vector_type(8)));
typedef float f32x4 __attribute__((ext_vector_type(4)));
typedef unsigned int u32;
typedef unsigned short u16;

#define DEV_INLINE __device__ __forceinline__

// ---------- constants ----------
#define S_LEN 2048
#define D_MODEL 4096
#define HQ 32
#define HK 8
#define HD 128
#define NQKV 6144   // HQ*HD + 2*HK*HD
#define QSCALE 0.08838834764831845f

DEV_INLINE u16 f2bf(float x) {
  union { float f; uint32_t u; } v; v.f = x;
  uint32_t r = v.u + 0x7FFFu + ((v.u >> 16) & 1u);  // RNE
  return (u16)(r >> 16);
}
DEV_INLINE float bf2f(u16 x) {
  union { uint32_t u; float f; } v; v.u = ((uint32_t)x) << 16;
  return v.f;
}
DEV_INLINE u32 pack2bf(float a, float b) {
  return (u32)f2bf(a) | ((u32)f2bf(b) << 16);
}

DEV_INLINE void async_load16(const void* g, void* l) {
  __builtin_amdgcn_global_load_lds(
      (const __attribute__((address_space(1))) u32*)g,
      (__attribute__((address_space(3))) u32*)l, 16, 0, 0);
}

DEV_INLINE f32x4 mfma16(bf16x8 a, bf16x8 b, f32x4 c) {
  return __builtin_amdgcn_mfma_f32_16x16x32_bf16(a, b, c, 0, 0, 0);
}

// ---------- prep: 4 weight transposes (f32 (4096,C) -> bf16 (C,4096)) + x cvt ----------
// segments (blocks): [0,16384) wq  [16384,20480) wk  [20480,24576) wv
//                    [24576,40960) wo  [40960,49152) x-cvt
__global__ __launch_bounds__(256) void prep(
    const float* __restrict__ wq, const float* __restrict__ wk,
    const float* __restrict__ wv, const float* __restrict__ wo,
    const float* __restrict__ x,
    u16* __restrict__ wt, u16* __restrict__ wot, u16* __restrict__ xb) {
  int b = blockIdx.x;
  if (b < 40960) {
    const float* src; u16* dst; int C;
    if (b < 16384)      { src = wq; dst = wt;                C = 4096; }
    else if (b < 20480) { src = wk; dst = wt + 4096L * 4096; C = 1024; b -= 16384; }
    else if (b < 24576) { src = wv; dst = wt + 5120L * 4096; C = 1024; b -= 20480; }
    else                { src = wo; dst = wot;               C = 4096; b -= 24576; }
    __shared__ float tile[32][33];
    int t = threadIdx.x, tx = t & 31, ty = t >> 5;
    int cbn = C >> 5;
    int c0 = (b % cbn) * 32, r0 = (b / cbn) * 32;
#pragma unroll
    for (int i = 0; i < 4; ++i)
      tile[ty + i * 8][tx] = src[(long)(r0 + ty + i * 8) * C + c0 + tx];
    __syncthreads();
#pragma unroll
    for (int i = 0; i < 4; ++i)
      dst[(long)(c0 + ty + i * 8) * 4096 + r0 + tx] = f2bf(tile[tx][ty + i * 8]);
  } else {
    int i = (b - 40960) * 1024 + threadIdx.x * 4;
    float4 v = *(const float4*)(x + i);
    union { u16 s[4]; uint2 u; } o;
    o.s[0] = f2bf(v.x); o.s[1] = f2bf(v.y); o.s[2] = f2bf(v.z); o.s[3] = f2bf(v.w);
    *(uint2*)(xb + i) = o.u;
  }
}

// ---------- RoPE on bf16 (strided input slice) -> packed bf16 ----------
__global__ void rope_bf16(const u16* __restrict__ in, const float* __restrict__ cosb,
                          const float* __restrict__ sinb, u16* __restrict__ out,
                          int H, int ld_in, int col_off, float scale) {
  int idx = blockIdx.x * blockDim.x + threadIdx.x;   // over S*H*64
  int j = idx & 63;
  int sh = idx >> 6;            // s*H + h
  int s = sh / H, h = sh - s * H;
  const u16* ip = in + (long)s * ld_in + col_off + h * HD;
  union { u32 u; u16 s2[2]; } v; v.u = *(const u32*)(ip + 2 * j);
  float q0 = bf2f(v.s2[0]), q1 = bf2f(v.s2[1]);
  float c = cosb[s * 64 + j], sn = sinb[s * 64 + j];
  *(u32*)(out + (long)sh * HD + 2 * j) =
      pack2bf((q0 * c - q1 * sn) * scale, (q0 * sn + q1 * c) * scale);
}

// ---------- transpose bf16 (R, ld_in cols, slice [col_off, col_off+C)) -> (C, R) ----------
__global__ void transpose_bf16(const u16* __restrict__ in, u16* __restrict__ out,
                               int R, int C, int ld_in, int col_off) {
  __shared__ u16 tile[32][33];
  int tx = threadIdx.x & 31, ty = threadIdx.x >> 5;  // block 256 = (32,8)
  int c0 = blockIdx.x * 32, r0 = blockIdx.y * 32;
#pragma unroll
  for (int i = 0; i < 4; ++i)
    tile[ty + i * 8][tx] = in[(long)(r0 + ty + i * 8) * ld_in + col_off + c0 + tx];
  __syncthreads();
#pragma unroll
  for (int i = 0; i < 4; ++i)
    out[(long)(c0 + ty + i * 8) * R + r0 + tx] = tile[tx][ty + i * 8];
}

// ---------- GEMM K-loop core (128x128 tile, BK=32, 4 waves) ----------
// 1D grid, bm-major swizzle: 16 consecutive block ids share one bn (B column),
// so co-dispatched blocks on one XCD hit the same B tile in its L2.
#define GEMM_KLOOP                                                              \
  __shared__ __attribute__((aligned(16))) u16 As[128 * 32];                     \
  __shared__ __attribute__((aligned(16))) u16 Bs[128 * 32];                     \
  const int tid = threadIdx.x;                                                  \
  const int lane = tid & 63, wave = tid >> 6;                                   \
  const int quad = lane >> 4, l15 = lane & 15;                                  \
  const int bm = blockIdx.x & 15, bn = blockIdx.x >> 4;                         \
  const int wr = (wave >> 1) * 64, wc = (wave & 1) * 64;                        \
  const long arow = (long)bm * 128, brow = (long)bn * 128;                      \
  f32x4 acc[4][4] = {};                                                         \
  for (int k0 = 0; k0 < K; k0 += 32) {                                          \
    _Pragma("unroll")                                                           \
    for (int t = 0; t < 2; ++t) {                                               \
      int c = tid + t * 256;                                                    \
      int row = c >> 2, cc = c & 3;                                             \
      int csrc = cc ^ (row & 3);                                                \
      async_load16(A + (arow + row) * K + k0 + csrc * 8, (u16*)As + c * 8);     \
      async_load16(Bt + (brow + row) * K + k0 + csrc * 8, (u16*)Bs + c * 8);    \
    }                                                                           \
    __syncthreads();                                                            \
    bf16x8 af[4], bfr[4];                                                       \
    _Pragma("unroll")                                                           \
    for (int i = 0; i < 4; ++i) {                                               \
      int row = wr + i * 16 + l15;                                              \
      af[i] = *(const bf16x8*)(As + row * 32 + ((quad ^ (row & 3)) * 8));       \
    }                                                                           \
    _Pragma("unroll")                                                           \
    for (int j = 0; j < 4; ++j) {                                               \
      int row = wc + j * 16 + l15;                                              \
      bfr[j] = *(const bf16x8*)(Bs + row * 32 + ((quad ^ (row & 3)) * 8));      \
    }                                                                           \
    _Pragma("unroll")                                                           \
    for (int i = 0; i < 4; ++i)                                                 \
      _Pragma("unroll")                                                         \
      for (int j = 0; j < 4; ++j)                                               \
        acc[i][j] = mfma16(af[i], bfr[j], acc[i][j]);                           \
    __syncthreads();                                                            \
  }

// C(M,N) bf16 = A(M,K)bf16 @ Bt(N,K)^T
__global__ __launch_bounds__(256) void gemm_bt_bf16(
    const u16* __restrict__ A, const u16* __restrict__ Bt, u16* __restrict__ C,
    int N, int K) {
  GEMM_KLOOP
#pragma unroll
  for (int i = 0; i < 4; ++i) {
    int row = bm * 128 + wr + i * 16 + quad * 4;
#pragma unroll
    for (int j = 0; j < 4; ++j) {
      int col = bn * 128 + wc + j * 16 + l15;
#pragma unroll
      for (int r = 0; r < 4; ++r)
        C[(long)(row + r) * N + col] = f2bf(acc[i][j][r]);
    }
  }
}

// C(M,N) f32 = A(M,K)bf16 @ Bt(N,K)^T
__global__ __launch_bounds__(256) void gemm_bt(
    const u16* __restrict__ A, const u16* __restrict__ Bt, float* __restrict__ C,
    int N, int K) {
  GEMM_KLOOP
#pragma unroll
  for (int i = 0; i < 4; ++i) {
    int row = bm * 128 + wr + i * 16 + quad * 4;
#pragma unroll
    for (int j = 0; j < 4; ++j) {
      int col = bn * 128 + wc + j * 16 + l15;
#pragma unroll
      for (int r = 0; r < 4; ++r)
        C[(long)(row + r) * N + col] = acc[i][j][r];
    }
  }
}

// ---------- flash attention (transposed formulation) ----------
// grid (16, HQ); 256 thr = 4 waves; q-tile 128, wave owns 32 q-rows (2 N-tiles).
// S^T = K @ Q^T ; O^T = V^T @ P^T. P^T via per-wave LDS, no barrier.
// LDS: Ks 32KB + Vs 32KB + Pts 16KB = 80KB -> 2 blocks/CU.
#define NEG_INF -1e30f
__global__ __launch_bounds__(256, 2) void attn_fwd(
    const u16* __restrict__ Qb, const u16* __restrict__ Kb,
    const u16* __restrict__ Vt, u16* __restrict__ Ob) {
  __shared__ __attribute__((aligned(16))) u16 Ks[128 * 128];    // kpos-major
  __shared__ __attribute__((aligned(16))) u16 Vs[128 * 128];    // d-major (V^T)
  __shared__ __attribute__((aligned(16))) u16 Pts[4][16 * 128]; // per-wave P^T
  const int tid = threadIdx.x;
  const int lane = tid & 63, wave = tid >> 6;
  const int quad = lane >> 4, l15 = lane & 15;
  const int u = 15 - blockIdx.x;        // heavy tiles dispatch first
  const int h = blockIdx.y, hk = h >> 2;
  const int swz = 2 * (l15 & 7);

  bf16x8 qf[2][4];
#pragma unroll
  for (int n = 0; n < 2; ++n) {
    const u16* qrow = Qb + (long)(u * 128 + wave * 32 + n * 16 + l15) * (HQ * HD)
                      + h * HD + quad * 8;
#pragma unroll
    for (int ks = 0; ks < 4; ++ks) qf[n][ks] = *(const bf16x8*)(qrow + ks * 32);
  }

  float m_run[2] = {NEG_INF, NEG_INF}, l_run[2] = {0.f, 0.f};
  f32x4 oacc[8][2] = {};

  for (int j = 0; j <= u; ++j) {
#pragma unroll
    for (int it = 0; it < 8; ++it) {
      int c = tid + it * 256;
      int row = c >> 4, cc = c & 15, csrc = cc ^ (row & 15);
      async_load16(Kb + (long)(j * 128 + row) * (HK * HD) + hk * HD + csrc * 8,
                   (u16*)Ks + c * 8);
      async_load16(Vt + (long)(hk * HD + row) * S_LEN + j * 128 + csrc * 8,
                   (u16*)Vs + c * 8);
    }
    __syncthreads();

    f32x4 sc[8][2] = {};
#pragma unroll
    for (int ks = 0; ks < 4; ++ks)
#pragma unroll
      for (int tj = 0; tj < 8; ++tj) {
        int row = tj * 16 + l15;
        bf16x8 kf = *(const bf16x8*)(Ks + row * 128 + (((ks * 4 + quad) ^ (row & 15)) * 8));
        sc[tj][0] = mfma16(kf, qf[0][ks], sc[tj][0]);
        sc[tj][1] = mfma16(kf, qf[1][ks], sc[tj][1]);
      }

    const bool diag = (j == u);
#pragma unroll
    for (int n = 0; n < 2; ++n) {
      int qloc = wave * 32 + n * 16 + l15;
      if (diag) {
#pragma unroll
        for (int tj = 0; tj < 8; ++tj)
#pragma unroll
          for (int r = 0; r < 4; ++r)
            if (tj * 16 + quad * 4 + r > qloc) sc[tj][n][r] = NEG_INF;
      }
      float m = NEG_INF;
#pragma unroll
      for (int tj = 0; tj < 8; ++tj)
#pragma unroll
        for (int r = 0; r < 4; ++r) m = fmaxf(m, sc[tj][n][r]);
      m = fmaxf(m, __shfl_xor(m, 16));
      m = fmaxf(m, __shfl_xor(m, 32));
      float mnew = fmaxf(m_run[n], m);
      float alpha = __expf(m_run[n] - mnew);
      m_run[n] = mnew;
      float rs = 0.f;
#pragma unroll
      for (int tj = 0; tj < 8; ++tj)
#pragma unroll
        for (int r = 0; r < 4; ++r) {
          float p = __expf(sc[tj][n][r] - mnew);
          sc[tj][n][r] = p;
          rs += p;
        }
      rs += __shfl_xor(rs, 16);
      rs += __shfl_xor(rs, 32);
      l_run[n] = l_run[n] * alpha + rs;
#pragma unroll
      for (int tj = 0; tj < 8; ++tj) oacc[tj][n] *= alpha;
    }

    u16* pw = &Pts[wave][0];
    bf16x8 pf0[4], pf1[4];
#pragma unroll
    for (int tj = 0; tj < 8; ++tj) {
      union { u32 w[2]; uint2 u2; } pk;
      pk.w[0] = pack2bf(sc[tj][0][0], sc[tj][0][1]);
      pk.w[1] = pack2bf(sc[tj][0][2], sc[tj][0][3]);
      *(uint2*)(pw + l15 * 128 + (((tj * 4 + quad) ^ swz) * 4)) = pk.u2;
    }
    __asm__ volatile("s_waitcnt lgkmcnt(0)" ::: "memory");
#pragma unroll
    for (int ks = 0; ks < 4; ++ks)
      pf0[ks] = *(const bf16x8*)(pw + l15 * 128 + (((ks * 8 + quad * 2) ^ swz) * 4));
    __asm__ volatile("s_waitcnt lgkmcnt(0)" ::: "memory");
#pragma unroll
    for (int tj = 0; tj < 8; ++tj) {
      union { u32 w[2]; uint2 u2; } pk;
      pk.w[0] = pack2bf(sc[tj][1][0], sc[tj][1][1]);
      pk.w[1] = pack2bf(sc[tj][1][2], sc[tj][1][3]);
      *(uint2*)(pw + l15 * 128 + (((tj * 4 + quad) ^ swz) * 4)) = pk.u2;
    }
    __asm__ volatile("s_waitcnt lgkmcnt(0)" ::: "memory");
#pragma unroll
    for (int ks = 0; ks < 4; ++ks)
      pf1[ks] = *(const bf16x8*)(pw + l15 * 128 + (((ks * 8 + quad * 2) ^ swz) * 4));

#pragma unroll
    for (int ks = 0; ks < 4; ++ks)
#pragma unroll
      for (int tj = 0; tj < 8; ++tj) {
        int row = tj * 16 + l15;
        bf16x8 vf = *(const bf16x8*)(Vs + row * 128 + (((ks * 4 + quad) ^ (row & 15)) * 8));
        oacc[tj][0] = mfma16(vf, pf0[ks], oacc[tj][0]);
        oacc[tj][1] = mfma16(vf, pf1[ks], oacc[tj][1]);
      }
    __syncthreads();
  }

#pragma unroll
  for (int n = 0; n < 2; ++n) {
    float inv_l = 1.0f / l_run[n];
    long grow = u * 128 + wave * 32 + n * 16 + l15;
#pragma unroll
    for (int tj = 0; tj < 8; ++tj) {
      int gcol = h * HD + tj * 16 + quad * 4;
      union { u32 w[2]; uint2 u2; } pk;
      pk.w[0] = pack2bf(oacc[tj][n][0] * inv_l, oacc[tj][n][1] * inv_l);
      pk.w[1] = pack2bf(oacc[tj][n][2] * inv_l, oacc[tj][n][3] * inv_l);
      *(uint2*)(Ob + grow * (HQ * HD) + gcol) = pk.u2;
    }
  }
}

// ---------- host ----------
#define MB (1024L * 1024L)

extern "C" void kernel_launch(void* const* d_in, const int* in_sizes, int n_in,
                              void* d_out, int out_size, void* d_ws, size_t ws_size,
                              hipStream_t stream) {
  const float* x    = (const float*)d_in[0];
  const float* fcos = (const float*)d_in[1];
  const float* fsin = (const float*)d_in[2];
  const float* wq   = (const float*)d_in[3];
  const float* wk   = (const float*)d_in[4];
  const float* wv   = (const float*)d_in[5];
  const float* wo   = (const float*)d_in[6];
  float* out = (float*)d_out;

  // Workspace layout (120 MB peak, wt region reused after the QKV GEMM):
  //   [0,48)   wt   -> after gemm_bt_bf16: Qb [0,16) Kb [16,20) Vt [20,24) attnb [24,40)
  //   [48,80)  wot (persists to final GEMM)
  //   [80,96)  xb
  //   [96,120) QKVb
  char* ws = (char*)d_ws;
  u16* wt    = (u16*)(ws + 0 * MB);
  u16* Qb    = (u16*)(ws + 0 * MB);
  u16* Kb    = (u16*)(ws + 16 * MB);
  u16* Vt    = (u16*)(ws + 20 * MB);
  u16* attnb = (u16*)(ws + 24 * MB);
  u16* wot   = (u16*)(ws + 48 * MB);
  u16* xb    = (u16*)(ws + 80 * MB);
  u16* QKVb  = (u16*)(ws + 96 * MB);

  // 1) all weight transposes + x cvt
  prep<<<49152, 256, 0, stream>>>(wq, wk, wv, wo, x, wt, wot, xb);

  // 2) fused QKV projection (bm-major swizzled grid: 48 bn x 16 bm)
  gemm_bt_bf16<<<(NQKV / 128) * (S_LEN / 128), 256, 0, stream>>>(xb, wt, QKVb, NQKV, D_MODEL);

  // 3) RoPE (scale folded into Q) + V^T from QKV slices
  rope_bf16<<<(S_LEN * HQ * 64) / 256, 256, 0, stream>>>(
      QKVb, fcos, fsin, Qb, HQ, NQKV, 0, QSCALE);
  rope_bf16<<<(S_LEN * HK * 64) / 256, 256, 0, stream>>>(
      QKVb, fcos, fsin, Kb, HK, NQKV, HQ * HD, 1.0f);
  transpose_bf16<<<dim3((HK * HD) / 32, S_LEN / 32), 256, 0, stream>>>(
      QKVb, Vt, S_LEN, HK * HD, NQKV, HQ * HD + HK * HD);

  // 4) flash attention
  attn_fwd<<<dim3(16, HQ), 256, 0, stream>>>(Qb, Kb, Vt, attnb);

  // 5) out = attn @ wo (bm-major swizzled grid: 32 bn x 16 bm)
  gemm_bt<<<(D_MODEL / 128) * (S_LEN / 128), 256, 0, stream>>>(attnb, wot, out, D_MODEL, HQ * HD);
}